// Round 5
// baseline (197.718 us; speedup 1.0000x reference)
//
#include <hip/hip_runtime.h>
#include <hip/hip_cooperative_groups.h>
#include <math.h>

namespace cg = cooperative_groups;

// CLAHE3D: B=C=1, D=H=W=128, GRID=8x8x8 (tiles 16^3, vpt=4096, nt=512), NB=64,
// bandwidth=0.001, clip=4.0 -> limit=256.
//
// Single cooperative kernel, 512 blocks x 256 threads (2 blocks/CU co-resident).
//   phase A: per-tile KDE hist -> clip/redistribute -> CDF   (block = tile)
//   grid.sync()
//   phase C: per block: build d-slice (fold i from L2-resident cdf), then 32
//            (d,h) rows: fold j in LDS, 6-tap bin spline, accs in registers;
//            block minmax partial
//   grid.sync()
//   all blocks reduce partials redundantly, normalize accs, single out write.
//
// ws layout (floats): cdf[8][64][64] @0 (32768) | bmm[512][2] @32768 (1024)

#define WS_CDF 0
#define WS_BMM 32768

__device__ __forceinline__ float bspline5(float x) {
    float t = fabsf(x);
    float t2 = t * t, t3 = t2 * t, t4 = t2 * t2, t5 = t4 * t;
    float w0 = 11.0f/20.0f - t2*0.5f + t4*0.25f - t5*(1.0f/12.0f);
    float w1 = 17.0f/40.0f + t*(5.0f/8.0f) - t2*(7.0f/4.0f) + t3*(5.0f/4.0f)
             - t4*(3.0f/8.0f) + t5*(1.0f/24.0f);
    float u = 3.0f - t;
    float w2 = u*u*u*u*u*(1.0f/120.0f);
    return t < 1.0f ? w0 : (t < 2.0f ? w1 : (t < 3.0f ? w2 : 0.0f));
}

// Branch-free quintic tap weights for u = frac(cb) in [0,1).
__device__ __forceinline__ void quintic_w(float u, float wb[6]) {
    float u2 = u*u, u4 = u2*u2, u5 = u4*u;
    float v = 1.0f - u;
    float v2 = v*v, v4 = v2*v2, v5 = v4*v;
    wb[0] = v5 * (1.0f/120.0f);
    wb[5] = u5 * (1.0f/120.0f);
    {
        float t = u + 1.0f;
        float t2 = t*t, t3 = t2*t, t4 = t2*t2, t5 = t4*t;
        wb[1] = 17.0f/40.0f + t*(5.0f/8.0f) - t2*(7.0f/4.0f) + t3*(5.0f/4.0f)
              - t4*(3.0f/8.0f) + t5*(1.0f/24.0f);
    }
    {
        float t = 2.0f - u;
        float t2 = t*t, t3 = t2*t, t4 = t2*t2, t5 = t4*t;
        wb[4] = 17.0f/40.0f + t*(5.0f/8.0f) - t2*(7.0f/4.0f) + t3*(5.0f/4.0f)
              - t4*(3.0f/8.0f) + t5*(1.0f/24.0f);
    }
    wb[2] = 11.0f/20.0f - u2*0.5f + u4*0.25f - u5*(1.0f/12.0f);
    wb[3] = 11.0f/20.0f - v2*0.5f + v4*0.25f - v5*(1.0f/12.0f);
}

__device__ __forceinline__ int reflect16(int t) {
    int r = t & 15;
    return r < 8 ? r : 15 - r;
}

__global__ __launch_bounds__(256, 2) void mega(const float* __restrict__ x,
                                               float* __restrict__ out,
                                               float* __restrict__ cdfbuf,
                                               float* __restrict__ bmm) {
    cg::grid_group grid = cg::this_grid();
    __shared__ float Ml[1024];                      // M[128][8]
    __shared__ float slice[4096];                   // d-slice [jk][n]
    __shared__ float t2T[2][2][512];                // dbuf x group: [k][n]
    __shared__ float hist[256];                     // 4 waves x 64 bins
    __shared__ float rmn[4], rmx[4], bc[2];

    const int tid = threadIdx.x;
    const int b = blockIdx.x;

    // ---- build axis matrix M in LDS ----
    if (tid < 128) {
        const float step = 8.0625f / 127.0f;        // linspace(-0.53125, 7.53125, 128)
        float c = -0.53125f + (float)tid * step;
        float row[8];
        #pragma unroll
        for (int i = 0; i < 8; ++i) row[i] = 0.0f;
        int base = (int)floorf(c) - 2;
        #pragma unroll
        for (int t = 0; t < 6; ++t) {
            int tap = base + t;
            row[reflect16(tap)] += bspline5(c - (float)tap);
        }
        #pragma unroll
        for (int i = 0; i < 8; ++i) Ml[tid * 8 + i] = row[i];
    }
    hist[tid] = 0.0f;
    __syncthreads();

    // ---- phase A: per-tile KDE hist -> clip/redistribute -> CDF ----
    // bandwidth=0.001 << bin spacing 1/63: only nearest bin representable in fp32.
    {
        int ti = b >> 6, tj = (b >> 3) & 7, tk = b & 7;
        int wv = tid >> 6;
        const float inv63 = 1.0f / 63.0f;
        int gbase4 = (((ti * 16) * 128 + tj * 16) * 128 + tk * 16) >> 2;
        const float4* x4 = (const float4*)x;
        #pragma unroll
        for (int itv = 0; itv < 4; ++itv) {
            int vi = itv * 256 + tid;               // 1024 float4 per tile
            int c4 = vi & 3, bb = (vi >> 2) & 15, a = vi >> 6;
            float4 v4 = x4[gbase4 + a * 4096 + bb * 32 + c4];
            float vals[4] = {v4.x, v4.y, v4.z, v4.w};
            #pragma unroll
            for (int m = 0; m < 4; ++m) {
                float val = vals[m];
                int b0 = (int)floorf(val * 63.0f + 0.5f);
                float q = (val - (float)b0 * inv63) * 1000.0f;
                atomicAdd(&hist[wv * 64 + b0], __expf(-0.5f * q * q));
            }
        }
        __syncthreads();
        if (tid < 64) {
            float pdf = (hist[tid] + hist[64 + tid] + hist[128 + tid] + hist[192 + tid])
                        * (1.0f / 4096.0f);
            float s = pdf;
            #pragma unroll
            for (int off = 32; off >= 1; off >>= 1) s += __shfl_xor(s, off, 64);
            float pdfn = pdf / (s + 1e-10f);
            float histo = fminf(pdfn * 4096.0f, 256.0f);
            float s2 = histo;
            #pragma unroll
            for (int off = 32; off >= 1; off >>= 1) s2 += __shfl_xor(s2, off, 64);
            float clipped = 4096.0f - s2;
            float residual = clipped - floorf(clipped * (1.0f / 64.0f)) * 64.0f;
            float redist = (clipped - residual) * (1.0f / 64.0f);
            float h2 = histo + redist + (((float)tid < residual) ? 1.0f : 0.0f);
            float cum = h2;
            #pragma unroll
            for (int off = 1; off < 64; off <<= 1) {
                float p = __shfl_up(cum, off, 64);
                if (tid >= off) cum += p;
            }
            cdfbuf[b * 64 + tid] = cum * (63.0f / 4096.0f);  // [i][jk][n]
        }
    }
    __threadfence();
    grid.sync();

    // ---- phase C: 32 rows per block, accs in registers ----
    float accs[16];
    float mn = 3.4e38f, mx = -3.4e38f;
    const int g = tid >> 7, lt = tid & 127;
    const int d = b >> 2;
    {
        // stage d-slice: slice[jk*64+n] = sum_i cdf[i][jk][n] * Md[d][i]
        // (cdf is 128 KB, L2-resident; 4x redundant compute beats a T1d pass)
        float md[8];
        #pragma unroll
        for (int i = 0; i < 8; ++i) md[i] = Ml[d * 8 + i];
        const float4* c4p = (const float4*)cdfbuf;
        float4* s4 = (float4*)slice;
        #pragma unroll
        for (int p = 0; p < 4; ++p) {
            int o4 = p * 256 + tid;                 // 1024 float4
            float4 acc4 = make_float4(0.f, 0.f, 0.f, 0.f);
            #pragma unroll
            for (int i = 0; i < 8; ++i) {
                float4 c = c4p[i * 1024 + o4];
                float m = md[i];
                acc4.x += c.x * m; acc4.y += c.y * m;
                acc4.z += c.z * m; acc4.w += c.w * m;
            }
            s4[o4] = acc4;
        }
        float mw[8];
        #pragma unroll
        for (int k = 0; k < 8; ++k) mw[k] = Ml[lt * 8 + k];
        __syncthreads();

        #pragma unroll
        for (int it = 0; it < 16; ++it) {
            int pair = b * 32 + it * 2 + g;         // d*128 + h
            int h = pair & 127;
            float mh[8];
            #pragma unroll
            for (int j = 0; j < 8; ++j) mh[j] = Ml[h * 8 + j];
            // j-fold (float4): t2T[k][n], o4 = lt covers 4 consecutive (k,n)
            float4 sacc = make_float4(0.f, 0.f, 0.f, 0.f);
            const float4* sl4 = (const float4*)slice;
            #pragma unroll
            for (int j = 0; j < 8; ++j) {
                float4 cv = sl4[j * 128 + lt];
                float m = mh[j];
                sacc.x += cv.x * m; sacc.y += cv.y * m;
                sacc.z += cv.z * m; sacc.w += cv.w * m;
            }
            int cur = it & 1;
            ((float4*)t2T[cur][g])[lt] = sacc;
            float v = x[pair * 128 + lt];
            __syncthreads();
            // bin-axis quintic spline at cb = v*63
            float cb = v * 63.0f;
            float fl = floorf(cb);
            int basei = (int)fl - 2;
            float wb[6];
            quintic_w(cb - fl, wb);
            float acc = 0.0f;
            #pragma unroll
            for (int tt = 0; tt < 6; ++tt) {
                int tap = basei + tt;               // in [-2, 66]
                int r = tap & 127;                  // reflect period 128
                int n = r < 64 ? r : 127 - r;
                const float* t2 = &t2T[cur][g][n];
                float s = 0.0f;
                #pragma unroll
                for (int k = 0; k < 8; ++k) s += t2[k * 64] * mw[k];
                acc += wb[tt] * s;
            }
            accs[it] = acc;
            mn = fminf(mn, acc);
            mx = fmaxf(mx, acc);
        }
    }
    // block minmax partial -> bmm[b]
    #pragma unroll
    for (int off = 32; off >= 1; off >>= 1) {
        mn = fminf(mn, __shfl_xor(mn, off, 64));
        mx = fmaxf(mx, __shfl_xor(mx, off, 64));
    }
    {
        int lane = tid & 63, wv = tid >> 6;
        if (lane == 0) { rmn[wv] = mn; rmx[wv] = mx; }
    }
    __syncthreads();
    if (tid == 0) {
        float a  = fminf(fminf(rmn[0], rmn[1]), fminf(rmn[2], rmn[3]));
        float bx = fmaxf(fmaxf(rmx[0], rmx[1]), fmaxf(rmx[2], rmx[3]));
        ((float2*)bmm)[b] = make_float2(a, bx);
    }
    __threadfence();
    grid.sync();

    // ---- global minmax (redundant per block) + normalize from registers ----
    {
        const float4* bm4 = (const float4*)bmm;     // 256 float4 = 512 float2
        float4 r = bm4[tid];
        float gmn = fminf(r.x, r.z), gmx = fmaxf(r.y, r.w);
        #pragma unroll
        for (int off = 32; off >= 1; off >>= 1) {
            gmn = fminf(gmn, __shfl_xor(gmn, off, 64));
            gmx = fmaxf(gmx, __shfl_xor(gmx, off, 64));
        }
        int lane = tid & 63, wv = tid >> 6;
        if (lane == 0) { rmn[wv] = gmn; rmx[wv] = gmx; }
        __syncthreads();
        if (tid == 0) {
            bc[0] = fminf(fminf(rmn[0], rmn[1]), fminf(rmn[2], rmn[3]));
            bc[1] = fmaxf(fmaxf(rmx[0], rmx[1]), fmaxf(rmx[2], rmx[3]));
        }
        __syncthreads();
        float m0 = bc[0];
        float sc = 1.0f / (bc[1] - m0 + 1e-10f);
        #pragma unroll
        for (int it = 0; it < 16; ++it) {
            int pair = b * 32 + it * 2 + g;
            out[pair * 128 + lt] = (accs[it] - m0) * sc;
        }
    }
}

extern "C" void kernel_launch(void* const* d_in, const int* in_sizes, int n_in,
                              void* d_out, int out_size, void* d_ws, size_t ws_size,
                              hipStream_t stream) {
    const float* x = (const float*)d_in[0];
    float* out = (float*)d_out;
    float* ws = (float*)d_ws;
    float* cdfbuf = ws + WS_CDF;
    float* bmmp   = ws + WS_BMM;

    void* args[] = {(void*)&x, (void*)&out, (void*)&cdfbuf, (void*)&bmmp};
    hipLaunchCooperativeKernel((void*)mega, dim3(512), dim3(256), args, 0, stream);
}

// Round 6
// 49.048 us; speedup vs baseline: 4.0311x; 4.0311x over previous
//
#include <hip/hip_runtime.h>
#include <math.h>

// CLAHE3D: B=C=1, D=H=W=128, GRID=8x8x8 (tiles 16^3, vpt=4096, nt=512), NB=64,
// bandwidth=0.001, clip=4.0 -> limit=256.
//
// 4 dispatches, no cooperative sync (grid.sync measured +150us on this chip):
//   k1: per-tile KDE hist -> clip/redistribute -> CDF; block 0 also builds M
//   k2: fold d-axis: T1d[d][jk][n]
//   k3: 2048 blocks x 8 rows: j-fold from L1/L2, bin spline, out + 2048 partials
//   k4: redundant partial reduce per block + in-place normalize
//
// ws layout (floats):
//   M    [128][8]    @0      (1024)
//   cdf  [8][64][64] @1024   (32768)  [i][jk][n], n innermost
//   T1d  [128][64][64] @33792 (524288) [d][jk][n]
//   bmm  [2048][2]   @558080 (4096)

#define WS_M    0
#define WS_CDF  1024
#define WS_T1D  (1024 + 32768)
#define WS_BMM  (1024 + 32768 + 524288)

__device__ __forceinline__ float bspline5(float x) {
    float t = fabsf(x);
    float t2 = t * t, t3 = t2 * t, t4 = t2 * t2, t5 = t4 * t;
    float w0 = 11.0f/20.0f - t2*0.5f + t4*0.25f - t5*(1.0f/12.0f);
    float w1 = 17.0f/40.0f + t*(5.0f/8.0f) - t2*(7.0f/4.0f) + t3*(5.0f/4.0f)
             - t4*(3.0f/8.0f) + t5*(1.0f/24.0f);
    float u = 3.0f - t;
    float w2 = u*u*u*u*u*(1.0f/120.0f);
    return t < 1.0f ? w0 : (t < 2.0f ? w1 : (t < 3.0f ? w2 : 0.0f));
}

// Branch-free quintic tap weights for u = frac(cb) in [0,1).
__device__ __forceinline__ void quintic_w(float u, float wb[6]) {
    float u2 = u*u, u4 = u2*u2, u5 = u4*u;
    float v = 1.0f - u;
    float v2 = v*v, v4 = v2*v2, v5 = v4*v;
    wb[0] = v5 * (1.0f/120.0f);
    wb[5] = u5 * (1.0f/120.0f);
    {
        float t = u + 1.0f;
        float t2 = t*t, t3 = t2*t, t4 = t2*t2, t5 = t4*t;
        wb[1] = 17.0f/40.0f + t*(5.0f/8.0f) - t2*(7.0f/4.0f) + t3*(5.0f/4.0f)
              - t4*(3.0f/8.0f) + t5*(1.0f/24.0f);
    }
    {
        float t = 2.0f - u;
        float t2 = t*t, t3 = t2*t, t4 = t2*t2, t5 = t4*t;
        wb[4] = 17.0f/40.0f + t*(5.0f/8.0f) - t2*(7.0f/4.0f) + t3*(5.0f/4.0f)
              - t4*(3.0f/8.0f) + t5*(1.0f/24.0f);
    }
    wb[2] = 11.0f/20.0f - u2*0.5f + u4*0.25f - u5*(1.0f/12.0f);
    wb[3] = 11.0f/20.0f - v2*0.5f + v4*0.25f - v5*(1.0f/12.0f);
}

// reflect (dct2) boundary for g=8 (period 16), taps in [-3, 10]
__device__ __forceinline__ int reflect16(int t) {
    int r = t & 15;
    return r < 8 ? r : 15 - r;
}

// ---------- k1: per-tile KDE histogram -> clip/redistribute -> CDF ----------
// bandwidth=0.001 << bin spacing 1/63: only the nearest bin gets a weight
// above ~e^-31 (2nd-nearest <= 2e-14, 3rd underflows fp32 exactly as in jnp).
// Block 0 additionally builds the axis matrix M[128][8] and writes it to ws.
__global__ __launch_bounds__(256) void k1_hist(const float* __restrict__ x,
                                               float* __restrict__ cdfbuf,
                                               float* __restrict__ M) {
    __shared__ float hist[256];                     // 4 waves x 64 bins
    __shared__ float Ml[1024];
    int t = threadIdx.x;
    int b = blockIdx.x;
    hist[t] = 0.0f;
    if (b == 0) {
        #pragma unroll
        for (int i = 0; i < 4; ++i) Ml[i * 256 + t] = 0.0f;
        __syncthreads();
        if (t < 128) {
            const float step = 8.0625f / 127.0f;    // linspace(-0.53125, 7.53125, 128)
            float c = -0.53125f + (float)t * step;
            int base = (int)floorf(c) - 2;
            #pragma unroll
            for (int tt = 0; tt < 6; ++tt) {        // per-thread-exclusive row: no race
                int tap = base + tt;
                Ml[t * 8 + reflect16(tap)] += bspline5(c - (float)tap);
            }
        }
        __syncthreads();
        #pragma unroll
        for (int i = 0; i < 4; ++i) M[i * 256 + t] = Ml[i * 256 + t];
    }
    __syncthreads();

    int ti = b >> 6, tj = (b >> 3) & 7, tk = b & 7;
    int wv = t >> 6;
    const float inv63 = 1.0f / 63.0f;
    int gbase4 = (((ti * 16) * 128 + tj * 16) * 128 + tk * 16) >> 2;
    const float4* x4 = (const float4*)x;
    #pragma unroll
    for (int itv = 0; itv < 4; ++itv) {
        int vi = itv * 256 + t;                     // 1024 float4 per tile
        int c4 = vi & 3, bb = (vi >> 2) & 15, a = vi >> 6;
        float4 v4 = x4[gbase4 + a * 4096 + bb * 32 + c4];
        float vals[4] = {v4.x, v4.y, v4.z, v4.w};
        #pragma unroll
        for (int m = 0; m < 4; ++m) {
            float val = vals[m];
            int b0 = (int)floorf(val * 63.0f + 0.5f);   // nearest bin, in [0,63]
            float q = (val - (float)b0 * inv63) * 1000.0f;
            atomicAdd(&hist[wv * 64 + b0], __expf(-0.5f * q * q));
        }
    }
    __syncthreads();

    if (t < 64) {                                   // one wave: clip/redistribute/CDF
        float pdf = (hist[t] + hist[64 + t] + hist[128 + t] + hist[192 + t])
                    * (1.0f / 4096.0f);
        float s = pdf;
        #pragma unroll
        for (int off = 32; off >= 1; off >>= 1) s += __shfl_xor(s, off, 64);
        float pdfn = pdf / (s + 1e-10f);
        float histo = fminf(pdfn * 4096.0f, 256.0f);
        float s2 = histo;
        #pragma unroll
        for (int off = 32; off >= 1; off >>= 1) s2 += __shfl_xor(s2, off, 64);
        float clipped = 4096.0f - s2;
        float residual = clipped - floorf(clipped * (1.0f / 64.0f)) * 64.0f;
        float redist = (clipped - residual) * (1.0f / 64.0f);
        float h2 = histo + redist + (((float)t < residual) ? 1.0f : 0.0f);
        float cum = h2;
        #pragma unroll
        for (int off = 1; off < 64; off <<= 1) {
            float p = __shfl_up(cum, off, 64);
            if (t >= off) cum += p;
        }
        cdfbuf[b * 64 + t] = cum * (63.0f / 4096.0f);   // [i][jk][n], coalesced
    }
}

// ---------- k2: fold d: T1d[d][jk][n] = sum_i cdf[i][jk][n] * M[d][i] (float4) ----------
__global__ __launch_bounds__(256) void k2_t1d(const float* __restrict__ cdfbuf,
                                              const float* __restrict__ M,
                                              float* __restrict__ T1d) {
    int i4 = blockIdx.x * 256 + threadIdx.x;        // 131072 float4 ids
    int d = i4 >> 10;                               // 1024 float4 per d
    int o4 = i4 & 1023;
    const float4* c4 = (const float4*)cdfbuf;
    float md[8];
    #pragma unroll
    for (int i = 0; i < 8; ++i) md[i] = M[d * 8 + i];
    float4 s = make_float4(0.f, 0.f, 0.f, 0.f);
    #pragma unroll
    for (int i = 0; i < 8; ++i) {
        float4 c = c4[i * 1024 + o4];
        s.x += c.x * md[i]; s.y += c.y * md[i];
        s.z += c.z * md[i]; s.w += c.w * md[i];
    }
    ((float4*)T1d)[i4] = s;
}

// ---------- k3: 2048 blocks x 8 (d,h) rows. j-fold from L1/L2 into t2T LDS,
//             branch-free 6-tap bin spline. Writes out + 2048 minmax partials. ----------
__global__ __launch_bounds__(256) void k3_final(const float* __restrict__ x,
                                                const float* __restrict__ T1d,
                                                const float* __restrict__ M,
                                                float* __restrict__ out,
                                                float* __restrict__ bmm) {
    __shared__ float t2T[2][2][512];                // dbuf x group: [k][n]
    __shared__ float smn[4], smx[4];
    int tid = threadIdx.x;
    int g = tid >> 7, lt = tid & 127;               // group, lane-in-group (= w)
    int b = blockIdx.x;
    int d = b >> 4;                                 // 16 blocks share each d -> L1 reuse

    float mw[8];
    #pragma unroll
    for (int k = 0; k < 8; ++k) mw[k] = M[lt * 8 + k];

    const float4* sl4 = (const float4*)(T1d + d * 4096);
    float accs[4];
    float mn = 3.4e38f, mx = -3.4e38f;

    #pragma unroll
    for (int it = 0; it < 4; ++it) {
        int pair = b * 8 + it * 2 + g;              // d*128 + h
        int h = pair & 127;
        float mh[8];
        #pragma unroll
        for (int j = 0; j < 8; ++j) mh[j] = M[h * 8 + j];
        // j-fold (float4, coalesced 2KB/group, L1-resident slice)
        float4 sacc = make_float4(0.f, 0.f, 0.f, 0.f);
        #pragma unroll
        for (int j = 0; j < 8; ++j) {
            float4 cv = sl4[j * 128 + lt];
            float m = mh[j];
            sacc.x += cv.x * m; sacc.y += cv.y * m;
            sacc.z += cv.z * m; sacc.w += cv.w * m;
        }
        int cur = it & 1;
        ((float4*)t2T[cur][g])[lt] = sacc;
        float v = x[pair * 128 + lt];
        __syncthreads();
        // bin-axis quintic spline at cb = v*63 (branch-free weights)
        float cb = v * 63.0f;
        float fl = floorf(cb);
        int basei = (int)fl - 2;
        float wb[6];
        quintic_w(cb - fl, wb);
        float acc = 0.0f;
        #pragma unroll
        for (int tt = 0; tt < 6; ++tt) {
            int tap = basei + tt;                   // in [-2, 66]
            int r = tap & 127;                      // reflect period 128
            int n = r < 64 ? r : 127 - r;
            const float* t2 = &t2T[cur][g][n];
            float s = 0.0f;
            #pragma unroll
            for (int k = 0; k < 8; ++k) s += t2[k * 64] * mw[k];
            acc += wb[tt] * s;
        }
        accs[it] = acc;
        mn = fminf(mn, acc);
        mx = fmaxf(mx, acc);
        out[pair * 128 + lt] = acc;
    }

    // block minmax partial -> bmm[b]
    #pragma unroll
    for (int off = 32; off >= 1; off >>= 1) {
        mn = fminf(mn, __shfl_xor(mn, off, 64));
        mx = fmaxf(mx, __shfl_xor(mx, off, 64));
    }
    int lane = tid & 63, wv = tid >> 6;
    if (lane == 0) { smn[wv] = mn; smx[wv] = mx; }
    __syncthreads();
    if (tid == 0) {
        float a  = fminf(fminf(smn[0], smn[1]), fminf(smn[2], smn[3]));
        float bx = fmaxf(fmaxf(smx[0], smx[1]), fmaxf(smx[2], smx[3]));
        ((float2*)bmm)[b] = make_float2(a, bx);
    }
}

// ---------- k4: redundant partial reduce + in-place normalize ----------
__global__ __launch_bounds__(256) void k4_norm(float* __restrict__ out,
                                               const float* __restrict__ bmm) {
    __shared__ float smn[4], smx[4], bc[2];
    int t = threadIdx.x;
    // reduce 2048 float2 = 1024 float4 (16 KB, L2-resident)
    const float4* bm4 = (const float4*)bmm;
    float mn = 3.4e38f, mx = -3.4e38f;
    #pragma unroll
    for (int i = 0; i < 4; ++i) {
        float4 r = bm4[i * 256 + t];
        mn = fminf(mn, fminf(r.x, r.z));
        mx = fmaxf(mx, fmaxf(r.y, r.w));
    }
    #pragma unroll
    for (int off = 32; off >= 1; off >>= 1) {
        mn = fminf(mn, __shfl_xor(mn, off, 64));
        mx = fmaxf(mx, __shfl_xor(mx, off, 64));
    }
    int lane = t & 63, wv = t >> 6;
    if (lane == 0) { smn[wv] = mn; smx[wv] = mx; }
    __syncthreads();
    if (t == 0) {
        bc[0] = fminf(fminf(smn[0], smn[1]), fminf(smn[2], smn[3]));
        bc[1] = fmaxf(fmaxf(smx[0], smx[1]), fmaxf(smx[2], smx[3]));
    }
    __syncthreads();
    float m0 = bc[0];
    float sc = 1.0f / (bc[1] - m0 + 1e-10f);
    int idx = blockIdx.x * 256 + t;                 // 524288 float4s
    float4* o4 = (float4*)out;
    float4 val = o4[idx];
    val.x = (val.x - m0) * sc;
    val.y = (val.y - m0) * sc;
    val.z = (val.z - m0) * sc;
    val.w = (val.w - m0) * sc;
    o4[idx] = val;
}

extern "C" void kernel_launch(void* const* d_in, const int* in_sizes, int n_in,
                              void* d_out, int out_size, void* d_ws, size_t ws_size,
                              hipStream_t stream) {
    const float* x = (const float*)d_in[0];
    float* out = (float*)d_out;
    float* ws = (float*)d_ws;
    float* M      = ws + WS_M;
    float* cdfbuf = ws + WS_CDF;
    float* T1d    = ws + WS_T1D;
    float* bmmp   = ws + WS_BMM;

    hipLaunchKernelGGL(k1_hist,  dim3(512),  dim3(256), 0, stream, x, cdfbuf, M);
    hipLaunchKernelGGL(k2_t1d,   dim3(512),  dim3(256), 0, stream, cdfbuf, M, T1d);
    hipLaunchKernelGGL(k3_final, dim3(2048), dim3(256), 0, stream, x, T1d, M, out, bmmp);
    hipLaunchKernelGGL(k4_norm,  dim3(2048), dim3(256), 0, stream, out, bmmp);
}